// Round 7
// baseline (25554.518 us; speedup 1.0000x reference)
//
#include <hip/hip_runtime.h>
#include <math.h>

// Problem constants (fixed by the harness).
#define BB 4096
#define TT 2048
#define LL 100

constexpr int NB = 8;        // batch items per block -> 512 blocks = 2 per CU (break phase-lock)
constexpr int WG = 512;      // 8 waves: 0-6 layer-1, 7 layer-2
constexpr int XTILE = 64;    // input timesteps staged per LDS tile
constexpr int XSTR = 12;     // xs_t row stride (dwords)
constexpr int HSTR = 108;    // h1 fp32 stride: (4*108)%32=16 -> conflict-free writes/reads
constexpr int WSTR = 104;    // W_ih2 LDS stride

#define LOG2E 1.44269504088896340736f

// afrag (M=8): element (m in [0,8), k=32kt+8q'+j) at dword kt*288 + row*8 + ((row>>2)<<2) + j,
// row = q'*8 + m in [0,32). b128 reads conflict-free (8-lane groups cover all 32 banks);
// scatter writes ~2-way (free per m136).
#define AOFF(kt, row) ((kt) * 288 + (row) * 8 + (((row) >> 2) << 2))

typedef short bf16x8 __attribute__((ext_vector_type(8)));
typedef float f32x4 __attribute__((ext_vector_type(4)));

union AF { int4 v; bf16x8 f; unsigned int w[4]; };

__device__ __forceinline__ unsigned int bf16rn(float x) {  // fp32 -> bf16 RNE
    unsigned int u = __float_as_uint(x);
    u += 0x7fffu + ((u >> 16) & 1u);
    return u >> 16;
}
__device__ __forceinline__ float bf16f(unsigned int h) { return __uint_as_float(h << 16); }
__device__ __forceinline__ float frcp(float x) { return __builtin_amdgcn_rcpf(x); }
__device__ __forceinline__ float fexp2(float x) {
#if __has_builtin(__builtin_amdgcn_exp2f)
    return __builtin_amdgcn_exp2f(x);
#else
    return exp2f(x);
#endif
}
// log2e is pre-folded into layer-1 weights/biases: v_exp_f32 IS 2^x, so the
// per-gate multiply disappears. sig2(x') = 1/(1+2^-x'); th2(x'') = 1-2/(1+2^x'').
__device__ __forceinline__ float sig2(float xp) { return frcp(1.0f + fexp2(-xp)); }
__device__ __forceinline__ float th2(float xpp) { return 1.0f - 2.0f * frcp(1.0f + fexp2(xpp)); }
__device__ __forceinline__ float ftanh_n(float x) { return th2(2.0f * LOG2E * x); }  // natural-domain tanh
__device__ __forceinline__ float fsig_n(float x) { return sig2(LOG2E * x); }

__device__ __forceinline__ unsigned int perm_lo(unsigned int w0, unsigned int w1) {
#if __has_builtin(__builtin_amdgcn_perm)
    return __builtin_amdgcn_perm(w1, w0, 0x05040100u);
#else
    return (w0 & 0xffffu) | (w1 << 16);
#endif
}
__device__ __forceinline__ unsigned int perm_hi(unsigned int w0, unsigned int w1) {
#if __has_builtin(__builtin_amdgcn_perm)
    return __builtin_amdgcn_perm(w1, w0, 0x07060302u);
#else
    return (w0 >> 16) | (w1 & 0xffff0000u);
#endif
}

// Layer-1: wave w (0..6) owns all 4 gates of units 16w..16w+15 (pad to 112);
// MFMA M=16 with items in rows 0..7 only (rows 8-15 zero, loads exec-masked).
// Frag layouts (HW-verified R4-R6): A[m=lane&15][k=32kt+8quad+j];
// B[k][n=lane&15]; D col=lane&15, row=quad*4+reg.
__global__ void __launch_bounds__(WG)
__attribute__((amdgpu_waves_per_eu(4, 4)))
lstm2_kernel(const float* __restrict__ input,   // [B,T]
             const float* __restrict__ W_ih1,   // [400,1]
             const float* __restrict__ W_hh1,   // [400,100]
             const float* __restrict__ b_ih1,   // [400]
             const float* __restrict__ b_hh1,   // [400]
             const float* __restrict__ W_ih2,   // [4,100]
             const float* __restrict__ W_hh2,   // [4,1]
             const float* __restrict__ b_ih2,   // [4]
             const float* __restrict__ b_hh2,   // [4]
             float* __restrict__ out)           // [B,T]
{
    __shared__ __align__(16) unsigned int afragP[2][1152];   // 9.2 KB (M=8 layout)
    __shared__ __align__(16) float h1f32[2][NB][HSTR];       // 6.9 KB
    __shared__ __align__(16) float xs_t[XTILE][XSTR];        // 3.0 KB (transposed input)
    __shared__ __align__(16) float wih2s[4][WSTR];           // 1.7 KB   => ~21 KB/block

    const int tid = threadIdx.x;
    const int wave = tid >> 6;
    const int lane = tid & 63;
    const int col16 = lane & 15;
    const int quad = lane >> 4;
    const int bg0 = blockIdx.x * NB;

    // ---------------- init ----------------
    for (int i = tid; i < 2 * 1152; i += WG) (&afragP[0][0])[i] = 0u;
    for (int i = tid; i < 2 * NB * HSTR; i += WG) (&h1f32[0][0][0])[i] = 0.0f;
    if (tid < 400) wih2s[tid / 100][tid % 100] = W_ih2[tid];

    const int uu = 16 * wave + col16;            // unit owned by this lane (waves 0-6)
    const bool uvalid = (wave < 7) && (uu < LL);

    // gate scales folding log2e (i,f,o: sigmoid; g: tanh needs 2x)
    const float gsc[4] = {LOG2E, LOG2E, 2.0f * LOG2E, LOG2E};

    // Persistent B-fragments: scaled W_hh1 bf16 hi/mid splits, 4 gates x 4 kt
    bf16x8 bhi[4][4], bmid[4][4];
#pragma unroll
    for (int g = 0; g < 4; ++g)
#pragma unroll
        for (int kt = 0; kt < 4; ++kt)
#pragma unroll
            for (int j = 0; j < 8; ++j) {
                const int k = 32 * kt + 8 * quad + j;
                float w = 0.0f;
                if (wave < 7 && uvalid && k < LL) w = W_hh1[(100 * g + uu) * LL + k] * gsc[g];
                const unsigned int hh = bf16rn(w);
                bhi[g][kt][j] = (short)hh;
                bmid[g][kt][j] = (short)bf16rn(w - bf16f(hh));
            }

    float wx[4], bs[4];
    float c1[4] = {0.f, 0.f, 0.f, 0.f};
#pragma unroll
    for (int g = 0; g < 4; ++g) {
        wx[g] = uvalid ? W_ih1[100 * g + uu] * gsc[g] : 0.0f;
        bs[g] = uvalid ? (b_ih1[100 * g + uu] + b_hh1[100 * g + uu]) * gsc[g] : 0.0f;
    }
    const int kt_u = uu >> 5;
    const int qp_u = (uu >> 3) & 3;   // q' for this unit
    const int j_u = uu & 7;

    // Layer-2 role (wave 7): lanes 0..31 = 8 items x 4 gates
    const int item = (lane >> 2) & 15;
    const int gg = lane & 3;
    const bool l2act = (wave == 7) && (lane < 32);
    float wh2 = 0.f, bs2 = 0.f, h2 = 0.f, c2 = 0.f;
    if (wave == 7) { wh2 = W_hh2[gg]; bs2 = b_ih2[gg] + b_hh2[gg]; }

    __syncthreads();

    // ---------------- time loop (one barrier per step) ----------------
    for (int t = 0; t <= TT; ++t) {
        const int p = t & 1, pn = p ^ 1;

        if (t < TT && (t & (XTILE - 1)) == 0) {
            const int m = tid >> 6, t0 = tid & 63;   // 512 threads = 8 items x 64 steps
            xs_t[t0][m] = input[(size_t)(bg0 + m) * TT + t + t0];
            __syncthreads();
        }

        if (t < TT && wave < 7) {
            // ---- load + unpack A-fragments (h1_{t-1}); rows 8-15 are zero ----
            const bool mvalid = col16 < 8;
            const int arow = quad * 8 + (lane & 7);
            AF ahi[4], alo[4];
#pragma unroll
            for (int kt = 0; kt < 4; ++kt) {
                int4 r0 = {0, 0, 0, 0}, r1 = {0, 0, 0, 0};
                if (mvalid) {
                    const unsigned int* ap = &afragP[p][AOFF(kt, arow)];
                    r0 = *(const int4*)ap;
                    r1 = *(const int4*)(ap + 4);
                }
                const unsigned int ww[8] = {(unsigned)r0.x, (unsigned)r0.y, (unsigned)r0.z, (unsigned)r0.w,
                                            (unsigned)r1.x, (unsigned)r1.y, (unsigned)r1.z, (unsigned)r1.w};
#pragma unroll
                for (int d = 0; d < 4; ++d) {
                    ahi[kt].w[d] = perm_lo(ww[2 * d], ww[2 * d + 1]);
                    alo[kt].w[d] = perm_hi(ww[2 * d], ww[2 * d + 1]);
                }
            }

            float act[4][4];  // [gate][r], valid for quad<2

            // ---- gate pair (i,f): MFMAs on all lanes, early activation on quads 0-1 ----
            {
                f32x4 a0 = (f32x4){0.f, 0.f, 0.f, 0.f}, a1 = a0;
#pragma unroll
                for (int kt = 0; kt < 4; ++kt) {
                    a0 = __builtin_amdgcn_mfma_f32_16x16x32_bf16(ahi[kt].f, bhi[0][kt], a0, 0, 0, 0);
                    a1 = __builtin_amdgcn_mfma_f32_16x16x32_bf16(ahi[kt].f, bhi[1][kt], a1, 0, 0, 0);
                }
#pragma unroll
                for (int kt = 0; kt < 4; ++kt) {
                    a0 = __builtin_amdgcn_mfma_f32_16x16x32_bf16(alo[kt].f, bhi[0][kt], a0, 0, 0, 0);
                    a1 = __builtin_amdgcn_mfma_f32_16x16x32_bf16(alo[kt].f, bhi[1][kt], a1, 0, 0, 0);
                }
#pragma unroll
                for (int kt = 0; kt < 4; ++kt) {
                    a0 = __builtin_amdgcn_mfma_f32_16x16x32_bf16(ahi[kt].f, bmid[0][kt], a0, 0, 0, 0);
                    a1 = __builtin_amdgcn_mfma_f32_16x16x32_bf16(ahi[kt].f, bmid[1][kt], a1, 0, 0, 0);
                }
                if (quad < 2) {
                    const float4 x4 = *(const float4*)&xs_t[t & (XTILE - 1)][4 * quad];
                    const float xr[4] = {x4.x, x4.y, x4.z, x4.w};
#pragma unroll
                    for (int r = 0; r < 4; ++r) {
                        act[0][r] = sig2(a0[r] + fmaf(wx[0], xr[r], bs[0]));
                        act[1][r] = sig2(a1[r] + fmaf(wx[1], xr[r], bs[1]));
                    }
                }
            }
            // ---- gate pair (g,o) ----
            {
                f32x4 a2 = (f32x4){0.f, 0.f, 0.f, 0.f}, a3 = a2;
#pragma unroll
                for (int kt = 0; kt < 4; ++kt) {
                    a2 = __builtin_amdgcn_mfma_f32_16x16x32_bf16(ahi[kt].f, bhi[2][kt], a2, 0, 0, 0);
                    a3 = __builtin_amdgcn_mfma_f32_16x16x32_bf16(ahi[kt].f, bhi[3][kt], a3, 0, 0, 0);
                }
#pragma unroll
                for (int kt = 0; kt < 4; ++kt) {
                    a2 = __builtin_amdgcn_mfma_f32_16x16x32_bf16(alo[kt].f, bhi[2][kt], a2, 0, 0, 0);
                    a3 = __builtin_amdgcn_mfma_f32_16x16x32_bf16(alo[kt].f, bhi[3][kt], a3, 0, 0, 0);
                }
#pragma unroll
                for (int kt = 0; kt < 4; ++kt) {
                    a2 = __builtin_amdgcn_mfma_f32_16x16x32_bf16(ahi[kt].f, bmid[2][kt], a2, 0, 0, 0);
                    a3 = __builtin_amdgcn_mfma_f32_16x16x32_bf16(ahi[kt].f, bmid[3][kt], a3, 0, 0, 0);
                }
                if (quad < 2) {
                    const float4 x4 = *(const float4*)&xs_t[t & (XTILE - 1)][4 * quad];
                    const float xr[4] = {x4.x, x4.y, x4.z, x4.w};
#pragma unroll
                    for (int r = 0; r < 4; ++r) {
                        act[2][r] = th2(-(a2[r] + fmaf(wx[2], xr[r], bs[2])));  // th2(x'')=1-2/(1+2^x''): tanh needs +x'' -> note sign
                        act[3][r] = sig2(a3[r] + fmaf(wx[3], xr[r], bs[3]));
                    }
                }
            }

            // ---- cell state + h write-back (quads 0-1 only; items m=4*quad+r) ----
            if (quad < 2) {
#pragma unroll
                for (int r = 0; r < 4; ++r) {
                    const int m = 4 * quad + r;
                    // act[2] computed as th2(-x'') = -tanh(x_g) ... fix sign here:
                    const float gv = -act[2][r];
                    const float c = act[1][r] * c1[r] + act[0][r] * gv;
                    c1[r] = c;
                    const float h = uvalid ? (act[3][r] * ftanh_n(c)) : 0.0f;
                    const unsigned int hh = bf16rn(h);
                    const unsigned int hl = bf16rn(h - bf16f(hh));
                    afragP[pn][AOFF(kt_u, qp_u * 8 + m) + j_u] = hh | (hl << 16);
                    if (uvalid) h1f32[pn][m][uu] = h;
                }
            }
        }

        // ---- layer 2 for step t-1 (wave 7, lanes 0-31; reads h1f32[p]) ----
        if (t >= 1 && l2act) {
            const float* hr = &h1f32[p][item][0];
            float a2 = 0.0f;
#pragma unroll
            for (int jb = 0; jb < 25; ++jb) {
                const float4 h4 = *(const float4*)(hr + 4 * jb);
                const float4 w4 = *(const float4*)&wih2s[gg][4 * jb];
                a2 = fmaf(h4.x, w4.x, a2);
                a2 = fmaf(h4.y, w4.y, a2);
                a2 = fmaf(h4.z, w4.z, a2);
                a2 = fmaf(h4.w, w4.w, a2);
            }
            const float pre2 = a2 + wh2 * h2 + bs2;
            const float v = (gg == 2) ? ftanh_n(pre2) : fsig_n(pre2);
            const int vb = __float_as_int(v);
            const float vi = __int_as_float(__builtin_amdgcn_mov_dpp(vb, 0x00, 0xF, 0xF, true));
            const float vf = __int_as_float(__builtin_amdgcn_mov_dpp(vb, 0x55, 0xF, 0xF, true));
            const float vg = __int_as_float(__builtin_amdgcn_mov_dpp(vb, 0xAA, 0xF, 0xF, true));
            const float vo = __int_as_float(__builtin_amdgcn_mov_dpp(vb, 0xFF, 0xF, 0xF, true));
            c2 = vf * c2 + vi * vg;
            h2 = vo * ftanh_n(c2);
            if (gg == 0) out[(size_t)(bg0 + item) * TT + (t - 1)] = h2;
        }

        __syncthreads();   // h1_t (afragP[pn], h1f32[pn]) visible for step t+1
    }
}

extern "C" void kernel_launch(void* const* d_in, const int* in_sizes, int n_in,
                              void* d_out, int out_size, void* d_ws, size_t ws_size,
                              hipStream_t stream) {
    const float* input = (const float*)d_in[0];
    const float* W_ih1 = (const float*)d_in[1];
    const float* W_hh1 = (const float*)d_in[2];
    const float* b_ih1 = (const float*)d_in[3];
    const float* b_hh1 = (const float*)d_in[4];
    const float* W_ih2 = (const float*)d_in[5];
    const float* W_hh2 = (const float*)d_in[6];
    const float* b_ih2 = (const float*)d_in[7];
    const float* b_hh2 = (const float*)d_in[8];
    float* out = (float*)d_out;

    dim3 grid(BB / NB);   // 512 workgroups -> 2 per CU (independent barriers)
    dim3 block(WG);       // 512 threads = 8 waves
    lstm2_kernel<<<grid, block, 0, stream>>>(input, W_ih1, W_hh1, b_ih1, b_hh1,
                                             W_ih2, W_hh2, b_ih2, b_hh2, out);
}

// Round 8
// 3150.916 us; speedup vs baseline: 8.1102x; 8.1102x over previous
//
#include <hip/hip_runtime.h>
#include <math.h>

// Problem constants (fixed by the harness).
#define BB 4096
#define TT 2048
#define LL 100

constexpr int NB = 16;       // batch items per block (= MFMA M)
constexpr int WG = 448;      // 7 waves, ALL layer-1; wave 3 also carries layer-2 (see below)
constexpr int XTILE = 64;    // input timesteps staged per LDS tile
constexpr int XSTR = 20;     // xs_t row stride (dwords)

#define L2E 1.44269504088896340736f

// afrag addressing (R6-proven): dword offset = kt*576 + row*8 + ((row>>2)<<2) + j.
// b128 reads conflict-free; packed-dword scatter writes <=2-way (free).
#define AOFF(kt, row) ((kt) * 576 + (row) * 8 + (((row) >> 2) << 2))

typedef short bf16x8 __attribute__((ext_vector_type(8)));
typedef float f32x4 __attribute__((ext_vector_type(4)));

union AF { int4 v; bf16x8 f; unsigned int w[4]; };

__device__ __forceinline__ unsigned int bf16rn(float x) {  // fp32 -> bf16 RNE
    unsigned int u = __float_as_uint(x);
    u += 0x7fffu + ((u >> 16) & 1u);
    return u >> 16;
}
__device__ __forceinline__ float bf16f(unsigned int h) { return __uint_as_float(h << 16); }
__device__ __forceinline__ float frcp(float x) { return __builtin_amdgcn_rcpf(x); }
__device__ __forceinline__ float fexp2(float x) {
#if __has_builtin(__builtin_amdgcn_exp2f)
    return __builtin_amdgcn_exp2f(x);
#else
    return exp2f(x);
#endif
}
// log2e pre-folded into weights/biases (v_exp_f32 IS 2^x).
// sig2(x') = 1/(1+2^-x')  [x' = log2e*x];  th2(x'') = 1-2/(1+2^x'') = tanh(x) for x''=2*log2e*x.
// Both saturate cleanly: exp2(inf)=inf -> rcp=0; exp2(-inf)=0.
__device__ __forceinline__ float sig2(float xp) { return frcp(1.0f + fexp2(-xp)); }
__device__ __forceinline__ float th2(float xpp) { return 1.0f - 2.0f * frcp(1.0f + fexp2(xpp)); }
__device__ __forceinline__ float ftanh_n(float x) { return th2(2.0f * L2E * x); }  // natural-arg tanh

__device__ __forceinline__ unsigned int perm_lo(unsigned int w0, unsigned int w1) {
#if __has_builtin(__builtin_amdgcn_perm)
    return __builtin_amdgcn_perm(w1, w0, 0x05040100u);
#else
    return (w0 & 0xffffu) | (w1 << 16);
#endif
}
__device__ __forceinline__ unsigned int perm_hi(unsigned int w0, unsigned int w1) {
#if __has_builtin(__builtin_amdgcn_perm)
    return __builtin_amdgcn_perm(w1, w0, 0x07060302u);
#else
    return (w0 >> 16) | (w1 & 0xffff0000u);
#endif
}

// Layer-1: gates padded 100->112 unit-slots; wave w owns all 4 gates of one
// 16-slot group. Slot-group permutation {0,1,2,6,3,4,5} puts the PAD group
// (slots 96..111, real units 96..99 only) on wave 3 -- the wave that sits
// alone on SIMD3 (7-wave block: SIMDs host waves {0,4},{1,5},{2,6},{3}).
// Layer-2 rides in the pad: B-column col16==8 of wave 3 holds W_ih2[g] for all
// four g, so the MFMA D-frag hands lane (w3,c8,quad) the full layer-2 preacts
// of items 4*quad..4*quad+3 (one step behind, like R4-R6's wave-7 pipeline).
// That kills wave 7, the h1f32 array (+462 LDS cyc/CU/step), and its barrier load.
// Frag layouts (HW-verified R4-R6): A[m=lane&15][k=32kt+8quad+j];
// B[k][n=lane&15]; D col=lane&15, row=quad*4+reg.
__global__ void __launch_bounds__(WG)
__attribute__((amdgpu_waves_per_eu(2, 2)))
lstm2_kernel(const float* __restrict__ input,   // [B,T]
             const float* __restrict__ W_ih1,   // [400,1]
             const float* __restrict__ W_hh1,   // [400,100]
             const float* __restrict__ b_ih1,   // [400]
             const float* __restrict__ b_hh1,   // [400]
             const float* __restrict__ W_ih2,   // [4,100]
             const float* __restrict__ W_hh2,   // [4,1]
             const float* __restrict__ b_ih2,   // [4]
             const float* __restrict__ b_hh2,   // [4]
             float* __restrict__ out)           // [B,T]
{
    __shared__ __align__(16) unsigned int afragP[2][2304];   // 18.4 KB packed h1 (hi|lo bf16)
    __shared__ __align__(16) float xs_t[XTILE][XSTR];        // 5.1 KB transposed input

    const int tid = threadIdx.x;
    const int wave = tid >> 6;       // 0..6
    const int lane = tid & 63;
    const int col16 = lane & 15;
    const int quad = lane >> 4;
    const int bg0 = blockIdx.x * NB;

    // ---------------- init ----------------
    for (int i = tid; i < 2 * 2304; i += WG) (&afragP[0][0])[i] = 0u;

    // slot-group permutation: wave 3 -> group 6 (slots 96..111)
    const int sb = (wave == 3) ? 6 : ((wave < 3) ? wave : wave - 1);
    const int uu = 16 * sb + col16;          // unit-slot owned by this lane
    const bool uvalid = (uu < LL);           // pad slots produce h=0
    const bool l2lane = (wave == 3) && (col16 == 8);   // layer-2 carrier lanes

    // gate scales folding log2e (i,f,o: sigmoid; g: tanh needs 2x)
    const float gsc[4] = {L2E, L2E, 2.0f * L2E, L2E};

    // Persistent B-fragments: bf16 hi/mid splits of scaled weights.
    // Normal lanes: W_hh1 rows; (w3,c8) lanes: W_ih2 rows (layer-2 in pad column).
    bf16x8 bhi[4][4], bmid[4][4];
#pragma unroll
    for (int g = 0; g < 4; ++g)
#pragma unroll
        for (int kt = 0; kt < 4; ++kt)
#pragma unroll
            for (int j = 0; j < 8; ++j) {
                const int k = 32 * kt + 8 * quad + j;
                float w = 0.0f;
                if (k < LL) {
                    if (l2lane)       w = W_ih2[g * LL + k] * gsc[g];
                    else if (uvalid)  w = W_hh1[(100 * g + uu) * LL + k] * gsc[g];
                }
                const unsigned int hh = bf16rn(w);
                bhi[g][kt][j] = (short)hh;
                bmid[g][kt][j] = (short)bf16rn(w - bf16f(hh));
            }

    float wx[4], bs[4];
    float c1[4] = {0.f, 0.f, 0.f, 0.f};
#pragma unroll
    for (int g = 0; g < 4; ++g) {
        wx[g] = uvalid ? W_ih1[100 * g + uu] * gsc[g] : 0.0f;
        bs[g] = uvalid ? (b_ih1[100 * g + uu] + b_hh1[100 * g + uu]) * gsc[g] : 0.0f;
    }
    const int kt_u = uu >> 5;
    const int lnb = ((uu >> 3) & 3) * 16;
    const int j_u = uu & 7;

    // Layer-2 recurrent state (l2lane only; 4 items per lane, m = 4*quad+r)
    float wh2s[4], bs2s[4], h2v[4] = {0.f, 0.f, 0.f, 0.f}, c2v[4] = {0.f, 0.f, 0.f, 0.f};
#pragma unroll
    for (int g = 0; g < 4; ++g) {
        wh2s[g] = l2lane ? W_hh2[g] * gsc[g] : 0.0f;
        bs2s[g] = l2lane ? (b_ih2[g] + b_hh2[g]) * gsc[g] : 0.0f;
    }

    __syncthreads();

    // ---------------- time loop (one barrier per step) ----------------
    for (int t = 0; t <= TT; ++t) {
        const int p = t & 1, pn = p ^ 1;

        if (t < TT && (t & (XTILE - 1)) == 0) {
            for (int i = tid; i < NB * XTILE; i += WG) {
                const int m = i >> 6, t2 = i & (XTILE - 1);
                xs_t[t2][m] = input[(size_t)(bg0 + m) * TT + t + t2];
            }
            __syncthreads();
        }

        // wave 3 also runs at t==TT to produce the final layer-2 output (step TT-1)
        if (t < TT || wave == 3) {
            // ---- load + v_perm unpack A-fragments (h1_{t-1}) ----
            AF ahi[4], alo[4];
#pragma unroll
            for (int kt = 0; kt < 4; ++kt) {
                const unsigned int* ap = &afragP[p][AOFF(kt, lane)];
                const int4 r0 = *(const int4*)ap;
                const int4 r1 = *(const int4*)(ap + 4);
                const unsigned int ww[8] = {(unsigned)r0.x, (unsigned)r0.y, (unsigned)r0.z, (unsigned)r0.w,
                                            (unsigned)r1.x, (unsigned)r1.y, (unsigned)r1.z, (unsigned)r1.w};
#pragma unroll
                for (int d = 0; d < 4; ++d) {
                    ahi[kt].w[d] = perm_lo(ww[2 * d], ww[2 * d + 1]);
                    alo[kt].w[d] = perm_hi(ww[2 * d], ww[2 * d + 1]);
                }
            }

            // ---- MFMA: 3-pass bf16 split, 4 independent gate chains ----
            f32x4 acc[4];
#pragma unroll
            for (int g = 0; g < 4; ++g) acc[g] = (f32x4){0.f, 0.f, 0.f, 0.f};
#pragma unroll
            for (int kt = 0; kt < 4; ++kt)
#pragma unroll
                for (int g = 0; g < 4; ++g)
                    acc[g] = __builtin_amdgcn_mfma_f32_16x16x32_bf16(ahi[kt].f, bhi[g][kt], acc[g], 0, 0, 0);
#pragma unroll
            for (int kt = 0; kt < 4; ++kt)
#pragma unroll
                for (int g = 0; g < 4; ++g)
                    acc[g] = __builtin_amdgcn_mfma_f32_16x16x32_bf16(alo[kt].f, bhi[g][kt], acc[g], 0, 0, 0);
#pragma unroll
            for (int kt = 0; kt < 4; ++kt)
#pragma unroll
                for (int g = 0; g < 4; ++g)
                    acc[g] = __builtin_amdgcn_mfma_f32_16x16x32_bf16(ahi[kt].f, bmid[g][kt], acc[g], 0, 0, 0);

            // ---- layer 2 (l2lane): acc[g][r] = dot(W_ih2[g], h1_{t-1}[item 4q+r]) ----
            if (l2lane && t >= 1) {
#pragma unroll
                for (int r = 0; r < 4; ++r) {
                    const float p0 = acc[0][r] + fmaf(wh2s[0], h2v[r], bs2s[0]);
                    const float p1 = acc[1][r] + fmaf(wh2s[1], h2v[r], bs2s[1]);
                    const float p2 = acc[2][r] + fmaf(wh2s[2], h2v[r], bs2s[2]);
                    const float p3 = acc[3][r] + fmaf(wh2s[3], h2v[r], bs2s[3]);
                    const float i2 = sig2(p0), f2 = sig2(p1), g2 = th2(p2), o2 = sig2(p3);
                    c2v[r] = f2 * c2v[r] + i2 * g2;
                    h2v[r] = o2 * ftanh_n(c2v[r]);
                    out[(size_t)(bg0 + 4 * quad + r) * TT + (t - 1)] = h2v[r];
                }
            }

            // ---- layer-1 cell update + h write-back ----
            if (t < TT) {
                const float4 x4 = *(const float4*)&xs_t[t & (XTILE - 1)][4 * quad];
                const float xr[4] = {x4.x, x4.y, x4.z, x4.w};
#pragma unroll
                for (int r = 0; r < 4; ++r) {
                    const int m = 4 * quad + r;
                    const float gi = acc[0][r] + fmaf(wx[0], xr[r], bs[0]);
                    const float gf = acc[1][r] + fmaf(wx[1], xr[r], bs[1]);
                    const float gG = acc[2][r] + fmaf(wx[2], xr[r], bs[2]);
                    const float go = acc[3][r] + fmaf(wx[3], xr[r], bs[3]);
                    const float iv = sig2(gi);
                    const float fv = sig2(gf);
                    const float gv = th2(gG);
                    const float ov = sig2(go);
                    const float c = fv * c1[r] + iv * gv;
                    c1[r] = c;
                    const float h = uvalid ? (ov * ftanh_n(c)) : 0.0f;  // pads stay 0
                    const unsigned int hh = bf16rn(h);
                    const unsigned int hl = bf16rn(h - bf16f(hh));
                    afragP[pn][AOFF(kt_u, lnb + m) + j_u] = hh | (hl << 16);
                }
            }
        }

        __syncthreads();   // h1_t (afragP[pn]) visible for step t+1
    }
}

extern "C" void kernel_launch(void* const* d_in, const int* in_sizes, int n_in,
                              void* d_out, int out_size, void* d_ws, size_t ws_size,
                              hipStream_t stream) {
    const float* input = (const float*)d_in[0];
    const float* W_ih1 = (const float*)d_in[1];
    const float* W_hh1 = (const float*)d_in[2];
    const float* b_ih1 = (const float*)d_in[3];
    const float* b_hh1 = (const float*)d_in[4];
    const float* W_ih2 = (const float*)d_in[5];
    const float* W_hh2 = (const float*)d_in[6];
    const float* b_ih2 = (const float*)d_in[7];
    const float* b_hh2 = (const float*)d_in[8];
    float* out = (float*)d_out;

    dim3 grid(BB / NB);   // 256 workgroups -> 1 per CU (weights fit VGPRs only once per CU)
    dim3 block(WG);       // 448 threads = 7 waves
    lstm2_kernel<<<grid, block, 0, stream>>>(input, W_ih1, W_hh1, b_ih1, b_hh1,
                                             W_ih2, W_hh2, b_ih2, b_hh2, out);
}